// Round 8
// baseline (292.551 us; speedup 1.0000x reference)
//
#include <hip/hip_runtime.h>
#include <hip/hip_bf16.h>
#include <math.h>

// Problem constants
#define Bz 2
#define Tz 512
#define Cz 2048
#define Hh 32
#define DH 64
#define NTOK (Bz * Tz)   // 1024
#define NCH 8            // chunks per sequence (Tz/64)
#define NSLICE 32        // split-K slices for the mix-LoRA GEMM (K-slice = 64)

typedef __hip_bfloat16 bf16;
typedef __attribute__((ext_vector_type(8))) short short8;
typedef __attribute__((ext_vector_type(4))) float f32x4;

// ---------------------------------------------------------------------------
__device__ __forceinline__ void load_lds16(const void* g, void* l) {
  __builtin_amdgcn_global_load_lds(
      (const __attribute__((address_space(1))) unsigned int*)g,
      (__attribute__((address_space(3))) unsigned int*)l,
      16, 0, 0);
}

__device__ __forceinline__ f32x4 bf4_to_f32(ushort4 u) {
  f32x4 r;
  r[0] = __builtin_bit_cast(float, (unsigned)u.x << 16);
  r[1] = __builtin_bit_cast(float, (unsigned)u.y << 16);
  r[2] = __builtin_bit_cast(float, (unsigned)u.z << 16);
  r[3] = __builtin_bit_cast(float, (unsigned)u.w << 16);
  return r;
}

__device__ __forceinline__ ushort4 f32_to_bf4(f32x4 s) {
  ushort4 u;
  u.x = __builtin_bit_cast(unsigned short, __float2bfloat16(s[0]));
  u.y = __builtin_bit_cast(unsigned short, __float2bfloat16(s[1]));
  u.z = __builtin_bit_cast(unsigned short, __float2bfloat16(s[2]));
  u.w = __builtin_bit_cast(unsigned short, __float2bfloat16(s[3]));
  return u;
}

// ---------------------------------------------------------------------------
// Shared MFMA GEMM core: A[M][K=2048] @ Bt[N][K]^T over k in [kBeg,kEnd).
// Caller provides LDS (As: MT*32, Bs: NT*32). 4 waves 2x2.
template <int MT, int NT>
__device__ __forceinline__ void gemm_core(
    bf16* As, bf16* Bs,
    const bf16* __restrict__ A, const bf16* __restrict__ Bt,
    int M0, int N0, int kBeg, int kEnd,
    f32x4 (&acc)[MT / 32][NT / 32]) {
  constexpr int AI = MT / 32, BJ = NT / 32;
  constexpr int TSA = MT / 16, TS = (MT + NT) / 16;
  static_assert(TS % 4 == 0, "strips must divide among 4 waves");
  int tid = threadIdx.x, lane = tid & 63, wave = tid >> 6;
  int wm = wave & 1, wn = wave >> 1;
  int srow = lane >> 2, scol = (lane & 3) * 8;
  int fr = lane & 15, fk = (lane >> 4) * 8;
  const bf16* rA = As + (wm * (MT / 2) + fr) * 32 + fk;
  const bf16* rB = Bs + (wn * (NT / 2) + fr) * 32 + fk;

  for (int k0 = kBeg; k0 < kEnd; k0 += 32) {
#pragma unroll
    for (int s = wave; s < TS; s += 4) {
      if (s < TSA)
        load_lds16(A + (size_t)(M0 + s * 16 + srow) * Cz + k0 + scol,
                   As + s * 16 * 32);
      else
        load_lds16(Bt + (size_t)(N0 + (s - TSA) * 16 + srow) * Cz + k0 + scol,
                   Bs + (s - TSA) * 16 * 32);
    }
    __syncthreads();
    short8 af[AI], bf[BJ];
#pragma unroll
    for (int i = 0; i < AI; i++) af[i] = *(const short8*)(rA + i * 16 * 32);
#pragma unroll
    for (int j = 0; j < BJ; j++) bf[j] = *(const short8*)(rB + j * 16 * 32);
#pragma unroll
    for (int i = 0; i < AI; i++)
#pragma unroll
      for (int j = 0; j < BJ; j++)
        acc[i][j] = __builtin_amdgcn_mfma_f32_16x16x32_bf16(af[i], bf[j],
                                                            acc[i][j], 0, 0, 0);
    __syncthreads();
  }
}

// ---------------------------------------------------------------------------
// Fused setup. Block = (32,8). Ranges:
// [0,16384)       big weight transposes (4 x 64 x 64 tiles)
// [16384,16768)   w1/tdw1 transposes
// [16768,17024)   maa_w2 -> w2t [4][2048][32] bf16
// [17024,17152)   td_w2  -> tdw2t [2048][64] bf16
// [17152,19200)   token-shift prep
__global__ __launch_bounds__(256) void k_setup(
    const float* __restrict__ qw, const float* __restrict__ kw,
    const float* __restrict__ vw, const float* __restrict__ ow,
    const float* __restrict__ w1, const float* __restrict__ tdw1,
    const float* __restrict__ w2, const float* __restrict__ tdw2,
    const float* __restrict__ x, const float* __restrict__ maa_x,
    bf16* __restrict__ qwt, bf16* __restrict__ kwt, bf16* __restrict__ vwt,
    bf16* __restrict__ owt, bf16* __restrict__ w1t, bf16* __restrict__ tdw1t,
    bf16* __restrict__ w2t, bf16* __restrict__ tdw2t,
    float* __restrict__ dx, bf16* __restrict__ xxxb) {
  __shared__ float tile[32][33];
  int bid = blockIdx.x;
  int tx = threadIdx.x, ty = threadIdx.y;
  if (bid < 16384) {
    int w = bid >> 12, r = bid & 4095;
    const float* W = w == 0 ? qw : w == 1 ? kw : w == 2 ? vw : ow;
    bf16* O = w == 0 ? qwt : w == 1 ? kwt : w == 2 ? vwt : owt;
    int bx = (r & 63) * 32, by = (r >> 6) * 32;
#pragma unroll
    for (int i = 0; i < 4; i++)
      tile[ty + 8 * i][tx] = W[(size_t)(by + ty + 8 * i) * Cz + bx + tx];
    __syncthreads();
#pragma unroll
    for (int i = 0; i < 4; i++)
      O[(size_t)(bx + ty + 8 * i) * Cz + by + tx] =
          __float2bfloat16(tile[tx][ty + 8 * i]);
  } else if (bid < 16768) {
    int r = bid - 16384;
    int z = r >> 6;           // 0..5
    int bk = (r & 63) * 32;
    const float* W;
    bf16* O;
    int N, bn;
    if (z < 4) { W = w1; O = w1t; N = 128; bn = z * 32; }
    else       { W = tdw1; O = tdw1t; N = 64; bn = (z - 4) * 32; }
#pragma unroll
    for (int i = 0; i < 4; i++)
      tile[ty + 8 * i][tx] = W[(size_t)(bk + ty + 8 * i) * N + bn + tx];
    __syncthreads();
#pragma unroll
    for (int i = 0; i < 4; i++)
      O[(size_t)(bn + ty + 8 * i) * Cz + bk + tx] =
          __float2bfloat16(tile[tx][ty + 8 * i]);
  } else if (bid < 17024) {
    int r2 = bid - 16768;
    int rr = r2 >> 6, c0 = (r2 & 63) * 32;
#pragma unroll
    for (int i = 0; i < 4; i++)
      tile[ty + 8 * i][tx] = w2[(size_t)(rr * 32 + ty + 8 * i) * Cz + c0 + tx];
    __syncthreads();
#pragma unroll
    for (int i = 0; i < 4; i++)
      w2t[(size_t)(rr * 2048 + c0 + ty + 8 * i) * 32 + tx] =
          __float2bfloat16(tile[tx][ty + 8 * i]);
  } else if (bid < 17152) {
    int r2 = bid - 17024;
    int k0 = (r2 & 1) * 32, c0 = (r2 >> 1) * 32;
#pragma unroll
    for (int i = 0; i < 4; i++)
      tile[ty + 8 * i][tx] = tdw2[(size_t)(k0 + ty + 8 * i) * Cz + c0 + tx];
    __syncthreads();
#pragma unroll
    for (int i = 0; i < 4; i++)
      tdw2t[(size_t)(c0 + ty + 8 * i) * 64 + k0 + tx] =
          __float2bfloat16(tile[tx][ty + 8 * i]);
  } else {
    int r = bid - 17152;
    int tid = ty * 32 + tx;
    int i4 = r * 256 + tid;
    int row = i4 >> 9, t = row & (Tz - 1), c4 = i4 & 511;
    const float4* x4 = (const float4*)x;
    float4 xv = x4[i4];
    float4 xp = make_float4(0.f, 0.f, 0.f, 0.f);
    if (t != 0) xp = x4[i4 - 512];
    float4 mx = ((const float4*)maa_x)[c4];
    float4 d, xx;
    d.x = xp.x - xv.x; d.y = xp.y - xv.y; d.z = xp.z - xv.z; d.w = xp.w - xv.w;
    xx.x = xv.x + d.x * mx.x; xx.y = xv.y + d.y * mx.y;
    xx.z = xv.z + d.z * mx.z; xx.w = xv.w + d.w * mx.w;
    ((float4*)dx)[i4] = d;
    ((ushort4*)xxxb)[i4] = f32_to_bf4((f32x4){xx.x, xx.y, xx.z, xx.w});
  }
}

// ---------------------------------------------------------------------------
// Split-K mix-LoRA GEMM: part[slice][1024][128] over K-slice of 64.
__global__ __launch_bounds__(256) void k_lora_gemm128(
    const bf16* __restrict__ A, const bf16* __restrict__ Bt,
    float* __restrict__ part) {
  __shared__ alignas(16) bf16 smem[256 * 32];
  constexpr int KS = Cz / NSLICE;  // 64
  f32x4 acc[4][4];
#pragma unroll
  for (int i = 0; i < 4; i++)
#pragma unroll
    for (int j = 0; j < 4; j++) acc[i][j] = (f32x4){0.f, 0.f, 0.f, 0.f};
  int bM = blockIdx.x, slice = blockIdx.y;
  gemm_core<128, 128>(smem, smem + 128 * 32, A, Bt, bM * 128, 0, slice * KS,
                      slice * KS + KS, acc);
  int lane = threadIdx.x & 63, wave = threadIdx.x >> 6;
  int wm = wave & 1, wn = wave >> 1;
  int r0 = (lane >> 4) * 4, cn = lane & 15;
#pragma unroll
  for (int i = 0; i < 4; i++) {
    int m = bM * 128 + wm * 64 + i * 16 + r0;
#pragma unroll
    for (int j = 0; j < 4; j++) {
      int n = wn * 64 + j * 16 + cn;
#pragma unroll
      for (int r = 0; r < 4; r++)
        part[((size_t)slice * NTOK + m + r) * 128 + n] = acc[i][j][r];
    }
  }
}

// ---------------------------------------------------------------------------
// out[i] = bf16(tanh(sum over NSLICE partials)).
__global__ __launch_bounds__(256) void k_reduce_tanh(
    const float* __restrict__ part, bf16* __restrict__ out, int n4) {
  int i = blockIdx.x * 256 + threadIdx.x;
  f32x4 s = (f32x4){0.f, 0.f, 0.f, 0.f};
#pragma unroll 8
  for (int sl = 0; sl < NSLICE; sl++)
    s += *(const f32x4*)&part[(size_t)sl * n4 * 4 + i * 4];
  f32x4 o = {tanhf(s[0]), tanhf(s[1]), tanhf(s[2]), tanhf(s[3])};
  ((ushort4*)out)[i] = f32_to_bf4(o);
}

// ---------------------------------------------------------------------------
// MFMA mproj: m_r = mmb[1024x128](slice r) @ w2t[r][2048x32]^T, K=32.
// Fused epilogue: px = bf16(x + dx*(maa + m)).  grid (16, 8, 4).
__global__ __launch_bounds__(256) void k_mproj_mfma(
    const bf16* __restrict__ mmb, const bf16* __restrict__ w2t,
    const float* __restrict__ x, const float* __restrict__ dx,
    const float* __restrict__ maa_r, const float* __restrict__ maa_k,
    const float* __restrict__ maa_v, const float* __restrict__ maa_w,
    bf16* __restrict__ pxr, bf16* __restrict__ pxk,
    bf16* __restrict__ pxv, bf16* __restrict__ pxw) {
  __shared__ alignas(16) bf16 As[128 * 32];
  __shared__ alignas(16) bf16 Bs[128 * 32];
  int r = blockIdx.z;
  int n0 = blockIdx.x * 128, m0 = blockIdx.y * 128;
  int tid = threadIdx.x, lane = tid & 63, wave = tid >> 6;
  int wm = wave & 1, wn = wave >> 1;
  int srow = lane >> 2, scol = (lane & 3) * 8;
#pragma unroll
  for (int s = wave; s < 16; s += 4) {
    if (s < 8)
      load_lds16(mmb + (size_t)(m0 + s * 16 + srow) * 128 + r * 32 + scol,
                 As + s * 16 * 32);
    else
      load_lds16(w2t + ((size_t)r * 2048 + n0 + (s - 8) * 16 + srow) * 32 + scol,
                 Bs + (s - 8) * 16 * 32);
  }
  __syncthreads();
  int fr = lane & 15, fk = (lane >> 4) * 8;
  const bf16* rA = As + (wm * 64 + fr) * 32 + fk;
  const bf16* rB = Bs + (wn * 64 + fr) * 32 + fk;
  f32x4 acc[4][4];
  short8 af[4], bf[4];
#pragma unroll
  for (int i = 0; i < 4; i++) af[i] = *(const short8*)(rA + i * 16 * 32);
#pragma unroll
  for (int j = 0; j < 4; j++) bf[j] = *(const short8*)(rB + j * 16 * 32);
#pragma unroll
  for (int i = 0; i < 4; i++)
#pragma unroll
    for (int j = 0; j < 4; j++)
      acc[i][j] = __builtin_amdgcn_mfma_f32_16x16x32_bf16(
          af[i], bf[j], (f32x4){0.f, 0.f, 0.f, 0.f}, 0, 0, 0);
  const float* maa = r == 0 ? maa_r : r == 1 ? maa_k : r == 2 ? maa_v : maa_w;
  bf16* dst = r == 0 ? pxr : r == 1 ? pxk : r == 2 ? pxv : pxw;
  int r0 = (lane >> 4) * 4, cn = lane & 15;
#pragma unroll
  for (int i = 0; i < 4; i++) {
    int m = m0 + wm * 64 + i * 16 + r0;
#pragma unroll
    for (int j = 0; j < 4; j++) {
      int n = n0 + wn * 64 + j * 16 + cn;
      float ma = maa[n];
#pragma unroll
      for (int rr = 0; rr < 4; rr++) {
        size_t idx = (size_t)(m + rr) * Cz + n;
        dst[idx] = __float2bfloat16(x[idx] + dx[idx] * (ma + acc[i][j][rr]));
      }
    }
  }
}

// ---------------------------------------------------------------------------
// Fused qkv split-K GEMM + unsplit decay-LoRA stage-1 GEMM.
// Blocks [0,8): twb = bf16(tanh(xwb @ tdw1t^T)), 128x64 tile, K=2048.
// Blocks [8,776): qkv partials, 128x128 tile, split-K=2, z = proj*2+slice.
__global__ __launch_bounds__(256) void k_qkv_lora(
    const bf16* __restrict__ xr, const bf16* __restrict__ xk,
    const bf16* __restrict__ xv, const bf16* __restrict__ qwt,
    const bf16* __restrict__ kwt, const bf16* __restrict__ vwt,
    bf16* __restrict__ part, const bf16* __restrict__ xwb,
    const bf16* __restrict__ tdw1t, bf16* __restrict__ twb) {
  __shared__ alignas(16) bf16 smem[256 * 32];
  int bid = blockIdx.x;
  int lane = threadIdx.x & 63, wave = threadIdx.x >> 6;
  int wm = wave & 1, wn = wave >> 1;
  int r0 = (lane >> 4) * 4, cn = lane & 15;
  if (bid < 8) {
    f32x4 acc[4][2];
#pragma unroll
    for (int i = 0; i < 4; i++)
#pragma unroll
      for (int j = 0; j < 2; j++) acc[i][j] = (f32x4){0.f, 0.f, 0.f, 0.f};
    gemm_core<128, 64>(smem, smem + 128 * 32, xwb, tdw1t, bid * 128, 0, 0, Cz,
                       acc);
#pragma unroll
    for (int i = 0; i < 4; i++) {
      int m = bid * 128 + wm * 64 + i * 16 + r0;
#pragma unroll
      for (int j = 0; j < 2; j++) {
        int n = wn * 32 + j * 16 + cn;
#pragma unroll
        for (int r = 0; r < 4; r++)
          twb[(size_t)(m + r) * 64 + n] =
              __float2bfloat16(tanhf(acc[i][j][r]));
      }
    }
  } else {
    int r = bid - 8;
    int z = r >> 7, xy = r & 127;
    int nx = xy & 15, my = xy >> 4;
    int proj = z >> 1, slice = z & 1;
    const bf16* A = proj == 0 ? xr : proj == 1 ? xk : xv;
    const bf16* W = proj == 0 ? qwt : proj == 1 ? kwt : vwt;
    f32x4 acc[4][4];
#pragma unroll
    for (int i = 0; i < 4; i++)
#pragma unroll
      for (int j = 0; j < 4; j++) acc[i][j] = (f32x4){0.f, 0.f, 0.f, 0.f};
    gemm_core<128, 128>(smem, smem + 128 * 32, A, W, my * 128, nx * 128,
                        slice * 1024, slice * 1024 + 1024, acc);
    bf16* dst = part + (size_t)z * NTOK * Cz;
#pragma unroll
    for (int i = 0; i < 4; i++) {
      int m = my * 128 + wm * 64 + i * 16 + r0;
#pragma unroll
      for (int j = 0; j < 4; j++) {
        int n = nx * 128 + wn * 64 + j * 16 + cn;
#pragma unroll
        for (int rr = 0; rr < 4; rr++)
          dst[(size_t)(m + rr) * Cz + n] = __float2bfloat16(acc[i][j][rr]);
      }
    }
  }
}

// ---------------------------------------------------------------------------
// MFMA tdB: acc = twb[1024x64] @ tdw2t[2048x64]^T, K=64 (2 phases).
// Epilogue: wlog = max(-exp(td + acc), -5).  grid (16, 8).
__global__ __launch_bounds__(256) void k_tdB_mfma(
    const bf16* __restrict__ twb, const bf16* __restrict__ tdw2t,
    const float* __restrict__ td, float* __restrict__ wlog) {
  __shared__ alignas(16) bf16 As[128 * 32];
  __shared__ alignas(16) bf16 Bs[128 * 32];
  int n0 = blockIdx.x * 128, m0 = blockIdx.y * 128;
  int tid = threadIdx.x, lane = tid & 63, wave = tid >> 6;
  int wm = wave & 1, wn = wave >> 1;
  int srow = lane >> 2, scol = (lane & 3) * 8;
  int fr = lane & 15, fk = (lane >> 4) * 8;
  const bf16* rA = As + (wm * 64 + fr) * 32 + fk;
  const bf16* rB = Bs + (wn * 64 + fr) * 32 + fk;
  f32x4 acc[4][4];
#pragma unroll
  for (int i = 0; i < 4; i++)
#pragma unroll
    for (int j = 0; j < 4; j++) acc[i][j] = (f32x4){0.f, 0.f, 0.f, 0.f};
  for (int k0 = 0; k0 < 64; k0 += 32) {
#pragma unroll
    for (int s = wave; s < 16; s += 4) {
      if (s < 8)
        load_lds16(twb + (size_t)(m0 + s * 16 + srow) * 64 + k0 + scol,
                   As + s * 16 * 32);
      else
        load_lds16(tdw2t + (size_t)(n0 + (s - 8) * 16 + srow) * 64 + k0 + scol,
                   Bs + (s - 8) * 16 * 32);
    }
    __syncthreads();
    short8 af[4], bf[4];
#pragma unroll
    for (int i = 0; i < 4; i++) af[i] = *(const short8*)(rA + i * 16 * 32);
#pragma unroll
    for (int j = 0; j < 4; j++) bf[j] = *(const short8*)(rB + j * 16 * 32);
#pragma unroll
    for (int i = 0; i < 4; i++)
#pragma unroll
      for (int j = 0; j < 4; j++)
        acc[i][j] = __builtin_amdgcn_mfma_f32_16x16x32_bf16(af[i], bf[j],
                                                            acc[i][j], 0, 0, 0);
    __syncthreads();
  }
  int r0 = (lane >> 4) * 4, cn = lane & 15;
#pragma unroll
  for (int i = 0; i < 4; i++) {
    int m = m0 + wm * 64 + i * 16 + r0;
#pragma unroll
    for (int j = 0; j < 4; j++) {
      int n = n0 + wn * 64 + j * 16 + cn;
      float tdc = td[n];
#pragma unroll
      for (int rr = 0; rr < 4; rr++) {
        float wl = -expf(tdc + acc[i][j][rr]);
        wlog[(size_t)(m + rr) * Cz + n] = fmaxf(wl, -5.0f);
      }
    }
  }
}

// ---------------------------------------------------------------------------
// Chunked GLA pass 1 with fused qkv-combine: q/k/v = partial sums + bias;
// k *= (1-exp(wlog)); cumsum; emit qt=q*0.125*exp(cum), kt=k*exp(-cum) bf16,
// aL=exp(cumL), U = Kh^T V.  512 blocks.
__global__ __launch_bounds__(256) void k_chunk_prep(
    const bf16* __restrict__ part, const float* __restrict__ qb,
    const float* __restrict__ kb, const float* __restrict__ vb,
    const float* __restrict__ wlog, bf16* __restrict__ qt,
    bf16* __restrict__ kt, float* __restrict__ aL, float* __restrict__ U) {
  __shared__ float sCum[64 * 64];
  __shared__ float sKh[64 * 64];
  __shared__ float sV[64 * 64];
  int tid = threadIdx.x;
  int bhc = blockIdx.x;
  int c = bhc & 7, h = (bhc >> 3) & 31, b = bhc >> 8;
  size_t gbase = ((size_t)(b * Tz) + c * 64) * Cz + h * 64;
  size_t cbase = (size_t)bhc * 4096;
  const ushort4* pp = (const ushort4*)part;
  const size_t P4 = (size_t)NTOK * Cz / 4;

#pragma unroll
  for (int i = 0; i < 4; i++) {
    int i4 = tid + i * 256;
    int t = i4 >> 4, dq = i4 & 15;
    size_t ge = gbase + (size_t)t * Cz + dq * 4;
    size_t gq = ge / 4;
    float4 kb4 = ((const float4*)kb)[h * 16 + dq];
    float4 vb4 = ((const float4*)vb)[h * 16 + dq];
    f32x4 kvv = bf4_to_f32(pp[2 * P4 + gq]) + bf4_to_f32(pp[3 * P4 + gq]) +
                (f32x4){kb4.x, kb4.y, kb4.z, kb4.w};
    f32x4 vvv = bf4_to_f32(pp[4 * P4 + gq]) + bf4_to_f32(pp[5 * P4 + gq]) +
                (f32x4){vb4.x, vb4.y, vb4.z, vb4.w};
    *(float4*)&sCum[t * 64 + dq * 4] = *(const float4*)&wlog[ge];
    *(f32x4*)&sKh[t * 64 + dq * 4] = kvv;
    *(f32x4*)&sV[t * 64 + dq * 4] = vvv;
  }
  __syncthreads();
#pragma unroll
  for (int i = 0; i < 16; i++) {
    int idx = tid + i * 256;
    sKh[idx] *= (1.f - expf(sCum[idx]));
  }
  __syncthreads();
  if (tid < 64) {
    float cum = 0.f;
#pragma unroll
    for (int t = 0; t < 64; t++) {
      cum += sCum[t * 64 + tid];
      sCum[t * 64 + tid] = cum;
    }
  }
  __syncthreads();
#pragma unroll
  for (int i = 0; i < 4; i++) {
    int i4 = tid + i * 256;
    int t = i4 >> 4, dq = i4 & 15;
    size_t ge = gbase + (size_t)t * Cz + dq * 4;
    size_t gq = ge / 4;
    float4 qb4 = ((const float4*)qb)[h * 16 + dq];
    f32x4 qv = (bf4_to_f32(pp[gq]) + bf4_to_f32(pp[P4 + gq]) +
                (f32x4){qb4.x, qb4.y, qb4.z, qb4.w}) * 0.125f;
    f32x4 cl = *(const f32x4*)&sCum[t * 64 + dq * 4];
    f32x4 cL = *(const f32x4*)&sCum[63 * 64 + dq * 4];
    f32x4 kraw = *(const f32x4*)&sKh[t * 64 + dq * 4];
    f32x4 qtv, ktv, khv;
#pragma unroll
    for (int e = 0; e < 4; e++) {
      qtv[e] = qv[e] * expf(cl[e]);
      ktv[e] = kraw[e] * expf(-cl[e]);
      khv[e] = kraw[e] * expf(cL[e] - cl[e]);
    }
    ((ushort4*)qt)[cbase / 4 + i4] = f32_to_bf4(qtv);
    ((ushort4*)kt)[cbase / 4 + i4] = f32_to_bf4(ktv);
    *(f32x4*)&sKh[t * 64 + dq * 4] = khv;
    if (t == 63) {
#pragma unroll
      for (int e = 0; e < 4; e++)
        aL[(size_t)bhc * 64 + dq * 4 + e] = expf(cl[e]);
    }
  }
  __syncthreads();
  int j = tid & 63, dg = tid >> 6;
  float acc[16];
#pragma unroll
  for (int dd = 0; dd < 16; dd++) acc[dd] = 0.f;
  for (int s = 0; s < 64; s++) {
    float vs = sV[s * 64 + j];
#pragma unroll
    for (int dd = 0; dd < 16; dd++)
      acc[dd] += sKh[s * 64 + dg * 16 + dd] * vs;
  }
#pragma unroll
  for (int dd = 0; dd < 16; dd++)
    U[cbase + (size_t)(dg * 16 + dd) * 64 + j] = acc[dd];
}

// ---------------------------------------------------------------------------
// Chunked GLA pass 2 (carry fused, v combined from partials).  512 blocks.
__global__ __launch_bounds__(256) void k_chunk_out(
    const bf16* __restrict__ qt, const bf16* __restrict__ kt,
    const bf16* __restrict__ part, const float* __restrict__ vb,
    const float* __restrict__ U, const float* __restrict__ aL,
    float* __restrict__ y) {
  __shared__ float sQ[64 * 65];
  __shared__ float sKS[64 * 65];  // k-tilde (stride 65), later S (stride 64)
  __shared__ float sP[64 * 65];
  __shared__ float sV[64 * 64];
  int tid = threadIdx.x;
  int bhc = blockIdx.x;
  int c = bhc & 7, h = (bhc >> 3) & 31, b = bhc >> 8;
  size_t gbase = ((size_t)(b * Tz) + c * 64) * Cz + h * 64;
  size_t cbase = (size_t)bhc * 4096;
  const ushort4* pp = (const ushort4*)part;
  const size_t P4 = (size_t)NTOK * Cz / 4;

#pragma unroll
  for (int i = 0; i < 4; i++) {
    int i4 = tid + i * 256;
    int t = i4 >> 4, dq = i4 & 15;
    ushort4 qu = *(const ushort4*)&qt[cbase + i4 * 4];
    ushort4 ku = *(const ushort4*)&kt[cbase + i4 * 4];
    *(f32x4*)&sQ[t * 65 + dq * 4] = bf4_to_f32(qu);
    *(f32x4*)&sKS[t * 65 + dq * 4] = bf4_to_f32(ku);
    size_t gq = (gbase + (size_t)t * Cz + dq * 4) / 4;
    float4 vb4 = ((const float4*)vb)[h * 16 + dq];
    f32x4 vvv = bf4_to_f32(pp[4 * P4 + gq]) + bf4_to_f32(pp[5 * P4 + gq]) +
                (f32x4){vb4.x, vb4.y, vb4.z, vb4.w};
    *(f32x4*)&sV[t * 64 + dq * 4] = vvv;
  }
  __syncthreads();
  int tg = tid & 15, sg = tid >> 4;
  float p[4][4];
#pragma unroll
  for (int i = 0; i < 4; i++)
#pragma unroll
    for (int jx = 0; jx < 4; jx++) p[i][jx] = 0.f;
  for (int d = 0; d < 64; d++) {
    float qv[4], kv[4];
#pragma unroll
    for (int i = 0; i < 4; i++) qv[i] = sQ[(tg * 4 + i) * 65 + d];
#pragma unroll
    for (int jx = 0; jx < 4; jx++) kv[jx] = sKS[(sg * 4 + jx) * 65 + d];
#pragma unroll
    for (int i = 0; i < 4; i++)
#pragma unroll
      for (int jx = 0; jx < 4; jx++) p[i][jx] += qv[i] * kv[jx];
  }
#pragma unroll
  for (int i = 0; i < 4; i++) {
    int t = tg * 4 + i;
#pragma unroll
    for (int jx = 0; jx < 4; jx++) {
      int s = sg * 4 + jx;
      sP[t * 65 + s] = (s <= t) ? p[i][jx] : 0.f;
    }
  }
  f32x4 Sreg[4];
#pragma unroll
  for (int i = 0; i < 4; i++) Sreg[i] = (f32x4){0.f, 0.f, 0.f, 0.f};
  for (int j = 0; j < c; j++) {
    int bhj = bhc - c + j;
    size_t ub = (size_t)bhj * 4096;
#pragma unroll
    for (int i = 0; i < 4; i++) {
      int i4 = tid + i * 256;
      int d = i4 >> 4;
      float a = aL[(size_t)bhj * 64 + d];
      f32x4 u = *(const f32x4*)&U[ub + (size_t)i4 * 4];
      Sreg[i] = Sreg[i] * a + u;
    }
  }
  __syncthreads();  // everyone done reading sKS as k-tilde
#pragma unroll
  for (int i = 0; i < 4; i++) {
    int i4 = tid + i * 256;
    int t = i4 >> 4, dq = i4 & 15;
    *(f32x4*)&sKS[t * 64 + dq * 4] = Sreg[i];
  }
  __syncthreads();
  f32x4 o[4];
#pragma unroll
  for (int i = 0; i < 4; i++) o[i] = (f32x4){0.f, 0.f, 0.f, 0.f};
  for (int s = 0; s < 64; s++) {
    f32x4 vv = *(const f32x4*)&sV[s * 64 + sg * 4];
#pragma unroll
    for (int i = 0; i < 4; i++) {
      float pv = sP[(tg * 4 + i) * 65 + s];
      o[i] += pv * vv;
    }
  }
  for (int d = 0; d < 64; d++) {
    f32x4 sv = *(const f32x4*)&sKS[d * 64 + sg * 4];
#pragma unroll
    for (int i = 0; i < 4; i++) {
      float qv = sQ[(tg * 4 + i) * 65 + d];
      o[i] += qv * sv;
    }
  }
#pragma unroll
  for (int i = 0; i < 4; i++) {
    int t = tg * 4 + i;
    *(f32x4*)&y[gbase + (size_t)t * Cz + sg * 4] = o[i];
  }
}

// ---------------------------------------------------------------------------
// LayerNorm over C, write bf16
__global__ __launch_bounds__(256) void k_ln(
    const float* __restrict__ y, const float* __restrict__ lg,
    const float* __restrict__ lb, bf16* __restrict__ yb) {
  __shared__ float red[8];
  int t = blockIdx.x;
  int tid = threadIdx.x;
  const float4* y4 = (const float4*)(y + (size_t)t * Cz);
  float4 vals[2];
  float s = 0.f, s2 = 0.f;
#pragma unroll
  for (int u = 0; u < 2; u++) {
    float4 a = y4[tid + 256 * u];
    vals[u] = a;
    s += a.x + a.y + a.z + a.w;
    s2 += a.x * a.x + a.y * a.y + a.z * a.z + a.w * a.w;
  }
#pragma unroll
  for (int off = 32; off > 0; off >>= 1) {
    s += __shfl_down(s, off);
    s2 += __shfl_down(s2, off);
  }
  if ((tid & 63) == 0) {
    red[(tid >> 6) * 2] = s;
    red[(tid >> 6) * 2 + 1] = s2;
  }
  __syncthreads();
  float ts = red[0] + red[2] + red[4] + red[6];
  float ts2 = red[1] + red[3] + red[5] + red[7];
  float mu = ts / (float)Cz;
  float var = ts2 / (float)Cz - mu * mu;
  float inv = rsqrtf(var + 1e-5f);
  bf16* outp = yb + (size_t)t * Cz;
#pragma unroll
  for (int u = 0; u < 2; u++) {
    int c0 = (tid + 256 * u) * 4;
    float4 a = vals[u];
    outp[c0 + 0] = __float2bfloat16((a.x - mu) * inv * lg[c0 + 0] + lb[c0 + 0]);
    outp[c0 + 1] = __float2bfloat16((a.y - mu) * inv * lg[c0 + 1] + lb[c0 + 1]);
    outp[c0 + 2] = __float2bfloat16((a.z - mu) * inv * lg[c0 + 2] + lb[c0 + 2]);
    outp[c0 + 3] = __float2bfloat16((a.w - mu) * inv * lg[c0 + 3] + lb[c0 + 3]);
  }
}

// ---------------------------------------------------------------------------
// Output projection, 128x128 tile, split-K=4, bf16 partials. grid (16,8,4).
__global__ __launch_bounds__(256) void k_gemm_o_split(
    const bf16* __restrict__ yb, const bf16* __restrict__ owt,
    bf16* __restrict__ part) {
  __shared__ alignas(16) bf16 smem[256 * 32];
  int z = blockIdx.z;
  f32x4 acc[4][4];
#pragma unroll
  for (int i = 0; i < 4; i++)
#pragma unroll
    for (int j = 0; j < 4; j++) acc[i][j] = (f32x4){0.f, 0.f, 0.f, 0.f};
  gemm_core<128, 128>(smem, smem + 128 * 32, yb, owt, blockIdx.y * 128,
                      blockIdx.x * 128, z * 512, z * 512 + 512, acc);
  int lane = threadIdx.x & 63, wave = threadIdx.x >> 6;
  int wm = wave & 1, wn = wave >> 1;
  int r0 = (lane >> 4) * 4, cn = lane & 15;
  bf16* dst = part + (size_t)z * NTOK * Cz;
#pragma unroll
  for (int i = 0; i < 4; i++) {
    int m = blockIdx.y * 128 + wm * 64 + i * 16 + r0;
#pragma unroll
    for (int j = 0; j < 4; j++) {
      int n = blockIdx.x * 128 + wn * 64 + j * 16 + cn;
#pragma unroll
      for (int r = 0; r < 4; r++)
        dst[(size_t)(m + r) * Cz + n] = __float2bfloat16(acc[i][j][r]);
    }
  }
}

__global__ __launch_bounds__(256) void k_combine_o(
    const bf16* __restrict__ part, float* __restrict__ out) {
  int i4 = blockIdx.x * 256 + threadIdx.x;
  const size_t P4 = (size_t)NTOK * Cz / 4;
  const ushort4* pp = (const ushort4*)part;
  f32x4 s = bf4_to_f32(pp[i4]) + bf4_to_f32(pp[P4 + i4]) +
            bf4_to_f32(pp[2 * P4 + i4]) + bf4_to_f32(pp[3 * P4 + i4]);
  *(f32x4*)&out[(size_t)i4 * 4] = s;
}

// ---------------------------------------------------------------------------
extern "C" void kernel_launch(void* const* d_in, const int* in_sizes, int n_in,
                              void* d_out, int out_size, void* d_ws,
                              size_t ws_size, hipStream_t stream) {
  const float* x      = (const float*)d_in[0];
  const float* maa_x  = (const float*)d_in[1];
  const float* maa_r  = (const float*)d_in[2];
  const float* maa_k  = (const float*)d_in[3];
  const float* maa_v  = (const float*)d_in[4];
  const float* maa_w  = (const float*)d_in[5];
  const float* maa_w1 = (const float*)d_in[6];
  const float* maa_w2 = (const float*)d_in[7];
  const float* tdcay  = (const float*)d_in[8];
  const float* td_w1  = (const float*)d_in[9];
  const float* td_w2  = (const float*)d_in[10];
  const float* q_w    = (const float*)d_in[11];
  const float* q_b    = (const float*)d_in[12];
  const float* k_w    = (const float*)d_in[13];
  const float* k_b    = (const float*)d_in[14];
  const float* v_w    = (const float*)d_in[15];
  const float* v_b    = (const float*)d_in[16];
  const float* ln_g   = (const float*)d_in[17];
  const float* ln_b   = (const float*)d_in[18];
  const float* o_w    = (const float*)d_in[19];
  float* out = (float*)d_out;

  char* p = (char*)d_ws;
  auto alloc = [&](size_t bytes) {
    char* r = p;
    p += (bytes + 255) & ~(size_t)255;
    return r;
  };
  const size_t WB = (size_t)Cz * Cz * sizeof(bf16);    // 8 MB
  const size_t AF = (size_t)NTOK * Cz * sizeof(float); // 8 MB
  const size_t AB = (size_t)NTOK * Cz * sizeof(bf16);  // 4 MB

  bf16* qwt = (bf16*)alloc(WB);
  bf16* kwt = (bf16*)alloc(WB);
  bf16* vwt = (bf16*)alloc(WB);
  bf16* owt = (bf16*)alloc(WB);
  char* xslot = (char*)alloc(AF);     // xxxb/w1t/tdw1t/w2t/tdw2t -> qt/kt
  char* mmslot = (char*)alloc((size_t)NTOK * 128 * sizeof(float));  // mmb/aL
  bf16* xr = (bf16*)alloc(AB);
  bf16* xk = (bf16*)alloc(AB);
  bf16* xv = (bf16*)alloc(AB);
  char* xwslot = (char*)alloc(AF);    // xwb -> U
  bf16* twb = (bf16*)alloc((size_t)NTOK * 64 * sizeof(bf16));
  float* wlog = (float*)alloc(AF);
  char* scratch24 = (char*)alloc(3 * AF);  // mm_part / qkv_part+y / o_part
  float* dx = (float*)alloc(AF);
  bf16* yb = (bf16*)alloc(AB);

  bf16* xxxb = (bf16*)xslot;
  bf16* w1t = (bf16*)(xslot + 4 * 1024 * 1024);
  bf16* tdw1t = (bf16*)(xslot + 4 * 1024 * 1024 + 512 * 1024);
  bf16* w2t = (bf16*)(xslot + 4 * 1024 * 1024 + 768 * 1024);
  bf16* tdw2t = (bf16*)(xslot + 4 * 1024 * 1024 + 1280 * 1024);
  bf16* qt = (bf16*)xslot;
  bf16* kt = (bf16*)(xslot + 4 * 1024 * 1024);
  bf16* xwb = (bf16*)xwslot;
  float* U = (float*)xwslot;
  bf16* mmb = (bf16*)mmslot;
  float* aLbuf = (float*)(mmslot + 256 * 1024);

  float* mm_part = (float*)scratch24;   // 16 MB, steps 2-3
  bf16* qkv_part = (bf16*)scratch24;    // 24 MB, steps 5-8 (slices 4,5 live to 8)
  float* y = (float*)scratch24;         // 8 MB, steps 8-9 (overwrites slices 0,1)
  bf16* o_part = (bf16*)scratch24;      // 16 MB, steps 10-11

  // 1. fused setup: weight transposes + token shift
  k_setup<<<19200, dim3(32, 8), 0, stream>>>(
      q_w, k_w, v_w, o_w, maa_w1, td_w1, maa_w2, td_w2, x, maa_x, qwt, kwt,
      vwt, owt, w1t, tdw1t, w2t, tdw2t, dx, xxxb);
  // 2-3. mix LoRA stage 1
  k_lora_gemm128<<<dim3(8, NSLICE), 256, 0, stream>>>(xxxb, w1t, mm_part);
  k_reduce_tanh<<<128, 256, 0, stream>>>(mm_part, mmb, NTOK * 128 / 4);
  // 4. mix LoRA stage 2 via MFMA, fused xr/xk/xv/xwb epilogue
  k_mproj_mfma<<<dim3(16, 8, 4), 256, 0, stream>>>(
      mmb, w2t, x, dx, maa_r, maa_k, maa_v, maa_w, xr, xk, xv, xwb);
  // 5. fused: qkv split-K partials + decay-LoRA stage 1 (tanh -> twb)
  k_qkv_lora<<<776, 256, 0, stream>>>(xr, xk, xv, qwt, kwt, vwt, qkv_part,
                                      xwb, tdw1t, twb);
  // 6. decay LoRA stage 2 via MFMA -> wlog
  k_tdB_mfma<<<dim3(16, 8), 256, 0, stream>>>(twb, tdw2t, tdcay, wlog);
  // 7. chunked GLA pass 1 (fused qkv combine + k-scale)
  k_chunk_prep<<<512, 256, 0, stream>>>(qkv_part, q_b, k_b, v_b, wlog, qt, kt,
                                        aLbuf, U);
  // 8. chunked GLA pass 2 (carry fused; v combined from partials)
  k_chunk_out<<<512, 256, 0, stream>>>(qt, kt, qkv_part, v_b, U, aLbuf, y);
  // 9. LayerNorm -> bf16
  k_ln<<<NTOK, 256, 0, stream>>>(y, ln_g, ln_b, yb);
  // 10-11. output projection: split-K=4 bf16 partials + combine
  k_gemm_o_split<<<dim3(16, 8, 4), 256, 0, stream>>>(yb, owt, o_part);
  k_combine_o<<<2048, 256, 0, stream>>>(o_part, out);
}

// Round 9
// 281.031 us; speedup vs baseline: 1.0410x; 1.0410x over previous
//
#include <hip/hip_runtime.h>
#include <hip/hip_bf16.h>
#include <math.h>

// Problem constants
#define Bz 2
#define Tz 512
#define Cz 2048
#define Hh 32
#define DH 64
#define NTOK (Bz * Tz)   // 1024
#define NCH 8            // chunks per sequence (Tz/64)
#define NSLICE 32        // split-K slices for LoRA GEMMs (K-slice = 64)

typedef __hip_bfloat16 bf16;
typedef __attribute__((ext_vector_type(8))) short short8;
typedef __attribute__((ext_vector_type(4))) float f32x4;

// ---------------------------------------------------------------------------
__device__ __forceinline__ void load_lds16(const void* g, void* l) {
  __builtin_amdgcn_global_load_lds(
      (const __attribute__((address_space(1))) unsigned int*)g,
      (__attribute__((address_space(3))) unsigned int*)l,
      16, 0, 0);
}

__device__ __forceinline__ f32x4 bf4_to_f32(ushort4 u) {
  f32x4 r;
  r[0] = __builtin_bit_cast(float, (unsigned)u.x << 16);
  r[1] = __builtin_bit_cast(float, (unsigned)u.y << 16);
  r[2] = __builtin_bit_cast(float, (unsigned)u.z << 16);
  r[3] = __builtin_bit_cast(float, (unsigned)u.w << 16);
  return r;
}

__device__ __forceinline__ ushort4 f32_to_bf4(f32x4 s) {
  ushort4 u;
  u.x = __builtin_bit_cast(unsigned short, __float2bfloat16(s[0]));
  u.y = __builtin_bit_cast(unsigned short, __float2bfloat16(s[1]));
  u.z = __builtin_bit_cast(unsigned short, __float2bfloat16(s[2]));
  u.w = __builtin_bit_cast(unsigned short, __float2bfloat16(s[3]));
  return u;
}

// ---------------------------------------------------------------------------
// Shared MFMA GEMM core: A[M][K=2048] @ Bt[N][K]^T over k in [kBeg,kEnd).
// Caller provides LDS (As: MT*32, Bs: NT*32). 4 waves 2x2.
template <int MT, int NT>
__device__ __forceinline__ void gemm_core(
    bf16* As, bf16* Bs,
    const bf16* __restrict__ A, const bf16* __restrict__ Bt,
    int M0, int N0, int kBeg, int kEnd,
    f32x4 (&acc)[MT / 32][NT / 32]) {
  constexpr int AI = MT / 32, BJ = NT / 32;
  constexpr int TSA = MT / 16, TS = (MT + NT) / 16;
  static_assert(TS % 4 == 0, "strips must divide among 4 waves");
  int tid = threadIdx.x, lane = tid & 63, wave = tid >> 6;
  int wm = wave & 1, wn = wave >> 1;
  int srow = lane >> 2, scol = (lane & 3) * 8;
  int fr = lane & 15, fk = (lane >> 4) * 8;
  const bf16* rA = As + (wm * (MT / 2) + fr) * 32 + fk;
  const bf16* rB = Bs + (wn * (NT / 2) + fr) * 32 + fk;

  for (int k0 = kBeg; k0 < kEnd; k0 += 32) {
#pragma unroll
    for (int s = wave; s < TS; s += 4) {
      if (s < TSA)
        load_lds16(A + (size_t)(M0 + s * 16 + srow) * Cz + k0 + scol,
                   As + s * 16 * 32);
      else
        load_lds16(Bt + (size_t)(N0 + (s - TSA) * 16 + srow) * Cz + k0 + scol,
                   Bs + (s - TSA) * 16 * 32);
    }
    __syncthreads();
    short8 af[AI], bf[BJ];
#pragma unroll
    for (int i = 0; i < AI; i++) af[i] = *(const short8*)(rA + i * 16 * 32);
#pragma unroll
    for (int j = 0; j < BJ; j++) bf[j] = *(const short8*)(rB + j * 16 * 32);
#pragma unroll
    for (int i = 0; i < AI; i++)
#pragma unroll
      for (int j = 0; j < BJ; j++)
        acc[i][j] = __builtin_amdgcn_mfma_f32_16x16x32_bf16(af[i], bf[j],
                                                            acc[i][j], 0, 0, 0);
    __syncthreads();
  }
}

// ---------------------------------------------------------------------------
// Fused setup. Block = (32,8). Ranges:
// [0,16384)       big weight transposes (4 x 64 x 64 tiles)
// [16384,16768)   w1/tdw1 transposes
// [16768,17024)   maa_w2 -> w2t [4][2048][32] bf16
// [17024,17152)   td_w2  -> tdw2t [2048][64] bf16
// [17152,19200)   token-shift prep
__global__ __launch_bounds__(256) void k_setup(
    const float* __restrict__ qw, const float* __restrict__ kw,
    const float* __restrict__ vw, const float* __restrict__ ow,
    const float* __restrict__ w1, const float* __restrict__ tdw1,
    const float* __restrict__ w2, const float* __restrict__ tdw2,
    const float* __restrict__ x, const float* __restrict__ maa_x,
    bf16* __restrict__ qwt, bf16* __restrict__ kwt, bf16* __restrict__ vwt,
    bf16* __restrict__ owt, bf16* __restrict__ w1t, bf16* __restrict__ tdw1t,
    bf16* __restrict__ w2t, bf16* __restrict__ tdw2t,
    float* __restrict__ dx, bf16* __restrict__ xxxb) {
  __shared__ float tile[32][33];
  int bid = blockIdx.x;
  int tx = threadIdx.x, ty = threadIdx.y;
  if (bid < 16384) {
    int w = bid >> 12, r = bid & 4095;
    const float* W = w == 0 ? qw : w == 1 ? kw : w == 2 ? vw : ow;
    bf16* O = w == 0 ? qwt : w == 1 ? kwt : w == 2 ? vwt : owt;
    int bx = (r & 63) * 32, by = (r >> 6) * 32;
#pragma unroll
    for (int i = 0; i < 4; i++)
      tile[ty + 8 * i][tx] = W[(size_t)(by + ty + 8 * i) * Cz + bx + tx];
    __syncthreads();
#pragma unroll
    for (int i = 0; i < 4; i++)
      O[(size_t)(bx + ty + 8 * i) * Cz + by + tx] =
          __float2bfloat16(tile[tx][ty + 8 * i]);
  } else if (bid < 16768) {
    int r = bid - 16384;
    int z = r >> 6;           // 0..5
    int bk = (r & 63) * 32;
    const float* W;
    bf16* O;
    int N, bn;
    if (z < 4) { W = w1; O = w1t; N = 128; bn = z * 32; }
    else       { W = tdw1; O = tdw1t; N = 64; bn = (z - 4) * 32; }
#pragma unroll
    for (int i = 0; i < 4; i++)
      tile[ty + 8 * i][tx] = W[(size_t)(bk + ty + 8 * i) * N + bn + tx];
    __syncthreads();
#pragma unroll
    for (int i = 0; i < 4; i++)
      O[(size_t)(bn + ty + 8 * i) * Cz + bk + tx] =
          __float2bfloat16(tile[tx][ty + 8 * i]);
  } else if (bid < 17024) {
    int r2 = bid - 16768;
    int rr = r2 >> 6, c0 = (r2 & 63) * 32;
#pragma unroll
    for (int i = 0; i < 4; i++)
      tile[ty + 8 * i][tx] = w2[(size_t)(rr * 32 + ty + 8 * i) * Cz + c0 + tx];
    __syncthreads();
#pragma unroll
    for (int i = 0; i < 4; i++)
      w2t[(size_t)(rr * 2048 + c0 + ty + 8 * i) * 32 + tx] =
          __float2bfloat16(tile[tx][ty + 8 * i]);
  } else if (bid < 17152) {
    int r2 = bid - 17024;
    int k0 = (r2 & 1) * 32, c0 = (r2 >> 1) * 32;
#pragma unroll
    for (int i = 0; i < 4; i++)
      tile[ty + 8 * i][tx] = tdw2[(size_t)(k0 + ty + 8 * i) * Cz + c0 + tx];
    __syncthreads();
#pragma unroll
    for (int i = 0; i < 4; i++)
      tdw2t[(size_t)(c0 + ty + 8 * i) * 64 + k0 + tx] =
          __float2bfloat16(tile[tx][ty + 8 * i]);
  } else {
    int r = bid - 17152;
    int tid = ty * 32 + tx;
    int i4 = r * 256 + tid;
    int row = i4 >> 9, t = row & (Tz - 1), c4 = i4 & 511;
    const float4* x4 = (const float4*)x;
    float4 xv = x4[i4];
    float4 xp = make_float4(0.f, 0.f, 0.f, 0.f);
    if (t != 0) xp = x4[i4 - 512];
    float4 mx = ((const float4*)maa_x)[c4];
    float4 d, xx;
    d.x = xp.x - xv.x; d.y = xp.y - xv.y; d.z = xp.z - xv.z; d.w = xp.w - xv.w;
    xx.x = xv.x + d.x * mx.x; xx.y = xv.y + d.y * mx.y;
    xx.z = xv.z + d.z * mx.z; xx.w = xv.w + d.w * mx.w;
    ((float4*)dx)[i4] = d;
    ((ushort4*)xxxb)[i4] = f32_to_bf4((f32x4){xx.x, xx.y, xx.z, xx.w});
  }
}

// ---------------------------------------------------------------------------
// Split-K mix-LoRA GEMM: part[slice][1024][128] over K-slice of 64.
__global__ __launch_bounds__(256) void k_lora_gemm128(
    const bf16* __restrict__ A, const bf16* __restrict__ Bt,
    float* __restrict__ part) {
  __shared__ alignas(16) bf16 smem[256 * 32];
  constexpr int KS = Cz / NSLICE;  // 64
  f32x4 acc[4][4];
#pragma unroll
  for (int i = 0; i < 4; i++)
#pragma unroll
    for (int j = 0; j < 4; j++) acc[i][j] = (f32x4){0.f, 0.f, 0.f, 0.f};
  int bM = blockIdx.x, slice = blockIdx.y;
  gemm_core<128, 128>(smem, smem + 128 * 32, A, Bt, bM * 128, 0, slice * KS,
                      slice * KS + KS, acc);
  int lane = threadIdx.x & 63, wave = threadIdx.x >> 6;
  int wm = wave & 1, wn = wave >> 1;
  int r0 = (lane >> 4) * 4, cn = lane & 15;
#pragma unroll
  for (int i = 0; i < 4; i++) {
    int m = bM * 128 + wm * 64 + i * 16 + r0;
#pragma unroll
    for (int j = 0; j < 4; j++) {
      int n = wn * 64 + j * 16 + cn;
#pragma unroll
      for (int r = 0; r < 4; r++)
        part[((size_t)slice * NTOK + m + r) * 128 + n] = acc[i][j][r];
    }
  }
}

// ---------------------------------------------------------------------------
// out[i] = bf16(tanh(sum over NSLICE partials)).
__global__ __launch_bounds__(256) void k_reduce_tanh(
    const float* __restrict__ part, bf16* __restrict__ out, int n4) {
  int i = blockIdx.x * 256 + threadIdx.x;
  f32x4 s = (f32x4){0.f, 0.f, 0.f, 0.f};
#pragma unroll 8
  for (int sl = 0; sl < NSLICE; sl++)
    s += *(const f32x4*)&part[(size_t)sl * n4 * 4 + i * 4];
  f32x4 o = {tanhf(s[0]), tanhf(s[1]), tanhf(s[2]), tanhf(s[3])};
  ((ushort4*)out)[i] = f32_to_bf4(o);
}

// ---------------------------------------------------------------------------
// MFMA mproj: m_r = mmb[1024x128](slice r) @ w2t[r][2048x32]^T, K=32.
// Fused epilogue: px = bf16(x + dx*(maa + m)).  grid (16, 8, 4).
__global__ __launch_bounds__(256) void k_mproj_mfma(
    const bf16* __restrict__ mmb, const bf16* __restrict__ w2t,
    const float* __restrict__ x, const float* __restrict__ dx,
    const float* __restrict__ maa_r, const float* __restrict__ maa_k,
    const float* __restrict__ maa_v, const float* __restrict__ maa_w,
    bf16* __restrict__ pxr, bf16* __restrict__ pxk,
    bf16* __restrict__ pxv, bf16* __restrict__ pxw) {
  __shared__ alignas(16) bf16 As[128 * 32];
  __shared__ alignas(16) bf16 Bs[128 * 32];
  int r = blockIdx.z;
  int n0 = blockIdx.x * 128, m0 = blockIdx.y * 128;
  int tid = threadIdx.x, lane = tid & 63, wave = tid >> 6;
  int wm = wave & 1, wn = wave >> 1;
  int srow = lane >> 2, scol = (lane & 3) * 8;
#pragma unroll
  for (int s = wave; s < 16; s += 4) {
    if (s < 8)
      load_lds16(mmb + (size_t)(m0 + s * 16 + srow) * 128 + r * 32 + scol,
                 As + s * 16 * 32);
    else
      load_lds16(w2t + ((size_t)r * 2048 + n0 + (s - 8) * 16 + srow) * 32 + scol,
                 Bs + (s - 8) * 16 * 32);
  }
  __syncthreads();
  int fr = lane & 15, fk = (lane >> 4) * 8;
  const bf16* rA = As + (wm * 64 + fr) * 32 + fk;
  const bf16* rB = Bs + (wn * 64 + fr) * 32 + fk;
  f32x4 acc[4][4];
  short8 af[4], bf[4];
#pragma unroll
  for (int i = 0; i < 4; i++) af[i] = *(const short8*)(rA + i * 16 * 32);
#pragma unroll
  for (int j = 0; j < 4; j++) bf[j] = *(const short8*)(rB + j * 16 * 32);
#pragma unroll
  for (int i = 0; i < 4; i++)
#pragma unroll
    for (int j = 0; j < 4; j++)
      acc[i][j] = __builtin_amdgcn_mfma_f32_16x16x32_bf16(
          af[i], bf[j], (f32x4){0.f, 0.f, 0.f, 0.f}, 0, 0, 0);
  const float* maa = r == 0 ? maa_r : r == 1 ? maa_k : r == 2 ? maa_v : maa_w;
  bf16* dst = r == 0 ? pxr : r == 1 ? pxk : r == 2 ? pxv : pxw;
  int r0 = (lane >> 4) * 4, cn = lane & 15;
#pragma unroll
  for (int i = 0; i < 4; i++) {
    int m = m0 + wm * 64 + i * 16 + r0;
#pragma unroll
    for (int j = 0; j < 4; j++) {
      int n = n0 + wn * 64 + j * 16 + cn;
      float ma = maa[n];
#pragma unroll
      for (int rr = 0; rr < 4; rr++) {
        size_t idx = (size_t)(m + rr) * Cz + n;
        dst[idx] = __float2bfloat16(x[idx] + dx[idx] * (ma + acc[i][j][rr]));
      }
    }
  }
}

// ---------------------------------------------------------------------------
// Fused qkv split-K GEMM + split-K decay-LoRA stage-1.
// Blocks [0,768): qkv partials, 128x128 tile, split-K=2, z = proj*2+slice.
// Blocks [768,1024): tw_part[slice][1024][64] = xwb @ tdw1t^T, K-slice 64.
__global__ __launch_bounds__(256) void k_qkv_lora(
    const bf16* __restrict__ xr, const bf16* __restrict__ xk,
    const bf16* __restrict__ xv, const bf16* __restrict__ qwt,
    const bf16* __restrict__ kwt, const bf16* __restrict__ vwt,
    bf16* __restrict__ part, const bf16* __restrict__ xwb,
    const bf16* __restrict__ tdw1t, float* __restrict__ tw_part) {
  __shared__ alignas(16) bf16 smem[256 * 32];
  int bid = blockIdx.x;
  int lane = threadIdx.x & 63, wave = threadIdx.x >> 6;
  int wm = wave & 1, wn = wave >> 1;
  int r0 = (lane >> 4) * 4, cn = lane & 15;
  if (bid < 768) {
    int z = bid >> 7, xy = bid & 127;
    int nx = xy & 15, my = xy >> 4;
    int proj = z >> 1, slice = z & 1;
    const bf16* A = proj == 0 ? xr : proj == 1 ? xk : xv;
    const bf16* W = proj == 0 ? qwt : proj == 1 ? kwt : vwt;
    f32x4 acc[4][4];
#pragma unroll
    for (int i = 0; i < 4; i++)
#pragma unroll
      for (int j = 0; j < 4; j++) acc[i][j] = (f32x4){0.f, 0.f, 0.f, 0.f};
    gemm_core<128, 128>(smem, smem + 128 * 32, A, W, my * 128, nx * 128,
                        slice * 1024, slice * 1024 + 1024, acc);
    bf16* dst = part + (size_t)z * NTOK * Cz;
#pragma unroll
    for (int i = 0; i < 4; i++) {
      int m = my * 128 + wm * 64 + i * 16 + r0;
#pragma unroll
      for (int j = 0; j < 4; j++) {
        int n = nx * 128 + wn * 64 + j * 16 + cn;
#pragma unroll
        for (int rr = 0; rr < 4; rr++)
          dst[(size_t)(m + rr) * Cz + n] = __float2bfloat16(acc[i][j][rr]);
      }
    }
  } else {
    int r = bid - 768;
    int bM = r & 7, slice = r >> 3;   // 8 M-tiles x 32 K-slices
    f32x4 acc[4][2];
#pragma unroll
    for (int i = 0; i < 4; i++)
#pragma unroll
      for (int j = 0; j < 2; j++) acc[i][j] = (f32x4){0.f, 0.f, 0.f, 0.f};
    gemm_core<128, 64>(smem, smem + 128 * 32, xwb, tdw1t, bM * 128, 0,
                       slice * 64, slice * 64 + 64, acc);
#pragma unroll
    for (int i = 0; i < 4; i++) {
      int m = bM * 128 + wm * 64 + i * 16 + r0;
#pragma unroll
      for (int j = 0; j < 2; j++) {
        int n = wn * 32 + j * 16 + cn;
#pragma unroll
        for (int rr = 0; rr < 4; rr++)
          tw_part[((size_t)slice * NTOK + m + rr) * 64 + n] = acc[i][j][rr];
      }
    }
  }
}

// ---------------------------------------------------------------------------
// MFMA tdB: acc = twb[1024x64] @ tdw2t[2048x64]^T, K=64 (2 phases).
// Epilogue: wlog = max(-exp(td + acc), -5).  grid (16, 8).
__global__ __launch_bounds__(256) void k_tdB_mfma(
    const bf16* __restrict__ twb, const bf16* __restrict__ tdw2t,
    const float* __restrict__ td, float* __restrict__ wlog) {
  __shared__ alignas(16) bf16 As[128 * 32];
  __shared__ alignas(16) bf16 Bs[128 * 32];
  int n0 = blockIdx.x * 128, m0 = blockIdx.y * 128;
  int tid = threadIdx.x, lane = tid & 63, wave = tid >> 6;
  int wm = wave & 1, wn = wave >> 1;
  int srow = lane >> 2, scol = (lane & 3) * 8;
  int fr = lane & 15, fk = (lane >> 4) * 8;
  const bf16* rA = As + (wm * 64 + fr) * 32 + fk;
  const bf16* rB = Bs + (wn * 64 + fr) * 32 + fk;
  f32x4 acc[4][4];
#pragma unroll
  for (int i = 0; i < 4; i++)
#pragma unroll
    for (int j = 0; j < 4; j++) acc[i][j] = (f32x4){0.f, 0.f, 0.f, 0.f};
  for (int k0 = 0; k0 < 64; k0 += 32) {
#pragma unroll
    for (int s = wave; s < 16; s += 4) {
      if (s < 8)
        load_lds16(twb + (size_t)(m0 + s * 16 + srow) * 64 + k0 + scol,
                   As + s * 16 * 32);
      else
        load_lds16(tdw2t + (size_t)(n0 + (s - 8) * 16 + srow) * 64 + k0 + scol,
                   Bs + (s - 8) * 16 * 32);
    }
    __syncthreads();
    short8 af[4], bf[4];
#pragma unroll
    for (int i = 0; i < 4; i++) af[i] = *(const short8*)(rA + i * 16 * 32);
#pragma unroll
    for (int j = 0; j < 4; j++) bf[j] = *(const short8*)(rB + j * 16 * 32);
#pragma unroll
    for (int i = 0; i < 4; i++)
#pragma unroll
      for (int j = 0; j < 4; j++)
        acc[i][j] = __builtin_amdgcn_mfma_f32_16x16x32_bf16(af[i], bf[j],
                                                            acc[i][j], 0, 0, 0);
    __syncthreads();
  }
  int r0 = (lane >> 4) * 4, cn = lane & 15;
#pragma unroll
  for (int i = 0; i < 4; i++) {
    int m = m0 + wm * 64 + i * 16 + r0;
#pragma unroll
    for (int j = 0; j < 4; j++) {
      int n = n0 + wn * 64 + j * 16 + cn;
      float tdc = td[n];
#pragma unroll
      for (int rr = 0; rr < 4; rr++) {
        float wl = -expf(tdc + acc[i][j][rr]);
        wlog[(size_t)(m + rr) * Cz + n] = fmaxf(wl, -5.0f);
      }
    }
  }
}

// ---------------------------------------------------------------------------
// Chunked GLA pass 1 with fused qkv-combine: q/k/v = partial sums + bias;
// k *= (1-exp(wlog)); cumsum; emit qt=q*0.125*exp(cum), kt=k*exp(-cum) bf16,
// aL=exp(cumL), U = Kh^T V.  512 blocks.
__global__ __launch_bounds__(256) void k_chunk_prep(
    const bf16* __restrict__ part, const float* __restrict__ qb,
    const float* __restrict__ kb, const float* __restrict__ vb,
    const float* __restrict__ wlog, bf16* __restrict__ qt,
    bf16* __restrict__ kt, float* __restrict__ aL, float* __restrict__ U) {
  __shared__ float sCum[64 * 64];
  __shared__ float sKh[64 * 64];
  __shared__ float sV[64 * 64];
  int tid = threadIdx.x;
  int bhc = blockIdx.x;
  int c = bhc & 7, h = (bhc >> 3) & 31, b = bhc >> 8;
  size_t gbase = ((size_t)(b * Tz) + c * 64) * Cz + h * 64;
  size_t cbase = (size_t)bhc * 4096;
  const ushort4* pp = (const ushort4*)part;
  const size_t P4 = (size_t)NTOK * Cz / 4;

#pragma unroll
  for (int i = 0; i < 4; i++) {
    int i4 = tid + i * 256;
    int t = i4 >> 4, dq = i4 & 15;
    size_t ge = gbase + (size_t)t * Cz + dq * 4;
    size_t gq = ge / 4;
    float4 kb4 = ((const float4*)kb)[h * 16 + dq];
    float4 vb4 = ((const float4*)vb)[h * 16 + dq];
    f32x4 kvv = bf4_to_f32(pp[2 * P4 + gq]) + bf4_to_f32(pp[3 * P4 + gq]) +
                (f32x4){kb4.x, kb4.y, kb4.z, kb4.w};
    f32x4 vvv = bf4_to_f32(pp[4 * P4 + gq]) + bf4_to_f32(pp[5 * P4 + gq]) +
                (f32x4){vb4.x, vb4.y, vb4.z, vb4.w};
    *(float4*)&sCum[t * 64 + dq * 4] = *(const float4*)&wlog[ge];
    *(f32x4*)&sKh[t * 64 + dq * 4] = kvv;
    *(f32x4*)&sV[t * 64 + dq * 4] = vvv;
  }
  __syncthreads();
#pragma unroll
  for (int i = 0; i < 16; i++) {
    int idx = tid + i * 256;
    sKh[idx] *= (1.f - expf(sCum[idx]));
  }
  __syncthreads();
  if (tid < 64) {
    float cum = 0.f;
#pragma unroll
    for (int t = 0; t < 64; t++) {
      cum += sCum[t * 64 + tid];
      sCum[t * 64 + tid] = cum;
    }
  }
  __syncthreads();
#pragma unroll
  for (int i = 0; i < 4; i++) {
    int i4 = tid + i * 256;
    int t = i4 >> 4, dq = i4 & 15;
    size_t ge = gbase + (size_t)t * Cz + dq * 4;
    size_t gq = ge / 4;
    float4 qb4 = ((const float4*)qb)[h * 16 + dq];
    f32x4 qv = (bf4_to_f32(pp[gq]) + bf4_to_f32(pp[P4 + gq]) +
                (f32x4){qb4.x, qb4.y, qb4.z, qb4.w}) * 0.125f;
    f32x4 cl = *(const f32x4*)&sCum[t * 64 + dq * 4];
    f32x4 cL = *(const f32x4*)&sCum[63 * 64 + dq * 4];
    f32x4 kraw = *(const f32x4*)&sKh[t * 64 + dq * 4];
    f32x4 qtv, ktv, khv;
#pragma unroll
    for (int e = 0; e < 4; e++) {
      qtv[e] = qv[e] * expf(cl[e]);
      ktv[e] = kraw[e] * expf(-cl[e]);
      khv[e] = kraw[e] * expf(cL[e] - cl[e]);
    }
    ((ushort4*)qt)[cbase / 4 + i4] = f32_to_bf4(qtv);
    ((ushort4*)kt)[cbase / 4 + i4] = f32_to_bf4(ktv);
    *(f32x4*)&sKh[t * 64 + dq * 4] = khv;
    if (t == 63) {
#pragma unroll
      for (int e = 0; e < 4; e++)
        aL[(size_t)bhc * 64 + dq * 4 + e] = expf(cl[e]);
    }
  }
  __syncthreads();
  int j = tid & 63, dg = tid >> 6;
  float acc[16];
#pragma unroll
  for (int dd = 0; dd < 16; dd++) acc[dd] = 0.f;
  for (int s = 0; s < 64; s++) {
    float vs = sV[s * 64 + j];
#pragma unroll
    for (int dd = 0; dd < 16; dd++)
      acc[dd] += sKh[s * 64 + dg * 16 + dd] * vs;
  }
#pragma unroll
  for (int dd = 0; dd < 16; dd++)
    U[cbase + (size_t)(dg * 16 + dd) * 64 + j] = acc[dd];
}

// ---------------------------------------------------------------------------
// Chunked GLA pass 2 (carry fused, v combined from partials).  512 blocks.
__global__ __launch_bounds__(256) void k_chunk_out(
    const bf16* __restrict__ qt, const bf16* __restrict__ kt,
    const bf16* __restrict__ part, const float* __restrict__ vb,
    const float* __restrict__ U, const float* __restrict__ aL,
    float* __restrict__ y) {
  __shared__ float sQ[64 * 65];
  __shared__ float sKS[64 * 65];  // k-tilde (stride 65), later S (stride 64)
  __shared__ float sP[64 * 65];
  __shared__ float sV[64 * 64];
  int tid = threadIdx.x;
  int bhc = blockIdx.x;
  int c = bhc & 7, h = (bhc >> 3) & 31, b = bhc >> 8;
  size_t gbase = ((size_t)(b * Tz) + c * 64) * Cz + h * 64;
  size_t cbase = (size_t)bhc * 4096;
  const ushort4* pp = (const ushort4*)part;
  const size_t P4 = (size_t)NTOK * Cz / 4;

#pragma unroll
  for (int i = 0; i < 4; i++) {
    int i4 = tid + i * 256;
    int t = i4 >> 4, dq = i4 & 15;
    ushort4 qu = *(const ushort4*)&qt[cbase + i4 * 4];
    ushort4 ku = *(const ushort4*)&kt[cbase + i4 * 4];
    *(f32x4*)&sQ[t * 65 + dq * 4] = bf4_to_f32(qu);
    *(f32x4*)&sKS[t * 65 + dq * 4] = bf4_to_f32(ku);
    size_t gq = (gbase + (size_t)t * Cz + dq * 4) / 4;
    float4 vb4 = ((const float4*)vb)[h * 16 + dq];
    f32x4 vvv = bf4_to_f32(pp[4 * P4 + gq]) + bf4_to_f32(pp[5 * P4 + gq]) +
                (f32x4){vb4.x, vb4.y, vb4.z, vb4.w};
    *(f32x4*)&sV[t * 64 + dq * 4] = vvv;
  }
  __syncthreads();
  int tg = tid & 15, sg = tid >> 4;
  float p[4][4];
#pragma unroll
  for (int i = 0; i < 4; i++)
#pragma unroll
    for (int jx = 0; jx < 4; jx++) p[i][jx] = 0.f;
  for (int d = 0; d < 64; d++) {
    float qv[4], kv[4];
#pragma unroll
    for (int i = 0; i < 4; i++) qv[i] = sQ[(tg * 4 + i) * 65 + d];
#pragma unroll
    for (int jx = 0; jx < 4; jx++) kv[jx] = sKS[(sg * 4 + jx) * 65 + d];
#pragma unroll
    for (int i = 0; i < 4; i++)
#pragma unroll
      for (int jx = 0; jx < 4; jx++) p[i][jx] += qv[i] * kv[jx];
  }
#pragma unroll
  for (int i = 0; i < 4; i++) {
    int t = tg * 4 + i;
#pragma unroll
    for (int jx = 0; jx < 4; jx++) {
      int s = sg * 4 + jx;
      sP[t * 65 + s] = (s <= t) ? p[i][jx] : 0.f;
    }
  }
  f32x4 Sreg[4];
#pragma unroll
  for (int i = 0; i < 4; i++) Sreg[i] = (f32x4){0.f, 0.f, 0.f, 0.f};
  for (int j = 0; j < c; j++) {
    int bhj = bhc - c + j;
    size_t ub = (size_t)bhj * 4096;
#pragma unroll
    for (int i = 0; i < 4; i++) {
      int i4 = tid + i * 256;
      int d = i4 >> 4;
      float a = aL[(size_t)bhj * 64 + d];
      f32x4 u = *(const f32x4*)&U[ub + (size_t)i4 * 4];
      Sreg[i] = Sreg[i] * a + u;
    }
  }
  __syncthreads();  // everyone done reading sKS as k-tilde
#pragma unroll
  for (int i = 0; i < 4; i++) {
    int i4 = tid + i * 256;
    int t = i4 >> 4, dq = i4 & 15;
    *(f32x4*)&sKS[t * 64 + dq * 4] = Sreg[i];
  }
  __syncthreads();
  f32x4 o[4];
#pragma unroll
  for (int i = 0; i < 4; i++) o[i] = (f32x4){0.f, 0.f, 0.f, 0.f};
  for (int s = 0; s < 64; s++) {
    f32x4 vv = *(const f32x4*)&sV[s * 64 + sg * 4];
#pragma unroll
    for (int i = 0; i < 4; i++) {
      float pv = sP[(tg * 4 + i) * 65 + s];
      o[i] += pv * vv;
    }
  }
  for (int d = 0; d < 64; d++) {
    f32x4 sv = *(const f32x4*)&sKS[d * 64 + sg * 4];
#pragma unroll
    for (int i = 0; i < 4; i++) {
      float qv = sQ[(tg * 4 + i) * 65 + d];
      o[i] += qv * sv;
    }
  }
#pragma unroll
  for (int i = 0; i < 4; i++) {
    int t = tg * 4 + i;
    *(f32x4*)&y[gbase + (size_t)t * Cz + sg * 4] = o[i];
  }
}

// ---------------------------------------------------------------------------
// LayerNorm over C, write bf16
__global__ __launch_bounds__(256) void k_ln(
    const float* __restrict__ y, const float* __restrict__ lg,
    const float* __restrict__ lb, bf16* __restrict__ yb) {
  __shared__ float red[8];
  int t = blockIdx.x;
  int tid = threadIdx.x;
  const float4* y4 = (const float4*)(y + (size_t)t * Cz);
  float4 vals[2];
  float s = 0.f, s2 = 0.f;
#pragma unroll
  for (int u = 0; u < 2; u++) {
    float4 a = y4[tid + 256 * u];
    vals[u] = a;
    s += a.x + a.y + a.z + a.w;
    s2 += a.x * a.x + a.y * a.y + a.z * a.z + a.w * a.w;
  }
#pragma unroll
  for (int off = 32; off > 0; off >>= 1) {
    s += __shfl_down(s, off);
    s2 += __shfl_down(s2, off);
  }
  if ((tid & 63) == 0) {
    red[(tid >> 6) * 2] = s;
    red[(tid >> 6) * 2 + 1] = s2;
  }
  __syncthreads();
  float ts = red[0] + red[2] + red[4] + red[6];
  float ts2 = red[1] + red[3] + red[5] + red[7];
  float mu = ts / (float)Cz;
  float var = ts2 / (float)Cz - mu * mu;
  float inv = rsqrtf(var + 1e-5f);
  bf16* outp = yb + (size_t)t * Cz;
#pragma unroll
  for (int u = 0; u < 2; u++) {
    int c0 = (tid + 256 * u) * 4;
    float4 a = vals[u];
    outp[c0 + 0] = __float2bfloat16((a.x - mu) * inv * lg[c0 + 0] + lb[c0 + 0]);
    outp[c0 + 1] = __float2bfloat16((a.y - mu) * inv * lg[c0 + 1] + lb[c0 + 1]);
    outp[c0 + 2] = __float2bfloat16((a.z - mu) * inv * lg[c0 + 2] + lb[c0 + 2]);
    outp[c0 + 3] = __float2bfloat16((a.w - mu) * inv * lg[c0 + 3] + lb[c0 + 3]);
  }
}

// ---------------------------------------------------------------------------
// Output projection, 128x128 tile, split-K=4, bf16 partials. grid (16,8,4).
__global__ __launch_bounds__(256) void k_gemm_o_split(
    const bf16* __restrict__ yb, const bf16* __restrict__ owt,
    bf16* __restrict__ part) {
  __shared__ alignas(16) bf16 smem[256 * 32];
  int z = blockIdx.z;
  f32x4 acc[4][4];
#pragma unroll
  for (int i = 0; i < 4; i++)
#pragma unroll
    for (int j = 0; j < 4; j++) acc[i][j] = (f32x4){0.f, 0.f, 0.f, 0.f};
  gemm_core<128, 128>(smem, smem + 128 * 32, yb, owt, blockIdx.y * 128,
                      blockIdx.x * 128, z * 512, z * 512 + 512, acc);
  int lane = threadIdx.x & 63, wave = threadIdx.x >> 6;
  int wm = wave & 1, wn = wave >> 1;
  int r0 = (lane >> 4) * 4, cn = lane & 15;
  bf16* dst = part + (size_t)z * NTOK * Cz;
#pragma unroll
  for (int i = 0; i < 4; i++) {
    int m = blockIdx.y * 128 + wm * 64 + i * 16 + r0;
#pragma unroll
    for (int j = 0; j < 4; j++) {
      int n = blockIdx.x * 128 + wn * 64 + j * 16 + cn;
#pragma unroll
      for (int r = 0; r < 4; r++)
        dst[(size_t)(m + r) * Cz + n] = __float2bfloat16(acc[i][j][r]);
    }
  }
}

__global__ __launch_bounds__(256) void k_combine_o(
    const bf16* __restrict__ part, float* __restrict__ out) {
  int i4 = blockIdx.x * 256 + threadIdx.x;
  const size_t P4 = (size_t)NTOK * Cz / 4;
  const ushort4* pp = (const ushort4*)part;
  f32x4 s = bf4_to_f32(pp[i4]) + bf4_to_f32(pp[P4 + i4]) +
            bf4_to_f32(pp[2 * P4 + i4]) + bf4_to_f32(pp[3 * P4 + i4]);
  *(f32x4*)&out[(size_t)i4 * 4] = s;
}

// ---------------------------------------------------------------------------
extern "C" void kernel_launch(void* const* d_in, const int* in_sizes, int n_in,
                              void* d_out, int out_size, void* d_ws,
                              size_t ws_size, hipStream_t stream) {
  const float* x      = (const float*)d_in[0];
  const float* maa_x  = (const float*)d_in[1];
  const float* maa_r  = (const float*)d_in[2];
  const float* maa_k  = (const float*)d_in[3];
  const float* maa_v  = (const float*)d_in[4];
  const float* maa_w  = (const float*)d_in[5];
  const float* maa_w1 = (const float*)d_in[6];
  const float* maa_w2 = (const float*)d_in[7];
  const float* tdcay  = (const float*)d_in[8];
  const float* td_w1  = (const float*)d_in[9];
  const float* td_w2  = (const float*)d_in[10];
  const float* q_w    = (const float*)d_in[11];
  const float* q_b    = (const float*)d_in[12];
  const float* k_w    = (const float*)d_in[13];
  const float* k_b    = (const float*)d_in[14];
  const float* v_w    = (const float*)d_in[15];
  const float* v_b    = (const float*)d_in[16];
  const float* ln_g   = (const float*)d_in[17];
  const float* ln_b   = (const float*)d_in[18];
  const float* o_w    = (const float*)d_in[19];
  float* out = (float*)d_out;

  char* p = (char*)d_ws;
  auto alloc = [&](size_t bytes) {
    char* r = p;
    p += (bytes + 255) & ~(size_t)255;
    return r;
  };
  const size_t WB = (size_t)Cz * Cz * sizeof(bf16);    // 8 MB
  const size_t AF = (size_t)NTOK * Cz * sizeof(float); // 8 MB
  const size_t AB = (size_t)NTOK * Cz * sizeof(bf16);  // 4 MB

  bf16* qwt = (bf16*)alloc(WB);
  bf16* kwt = (bf16*)alloc(WB);
  bf16* vwt = (bf16*)alloc(WB);
  bf16* owt = (bf16*)alloc(WB);
  char* xslot = (char*)alloc(AF);     // xxxb/w1t/tdw1t/w2t/tdw2t -> qt/kt
  char* mmslot = (char*)alloc((size_t)NTOK * 128 * sizeof(float));  // mmb/aL
  bf16* xr = (bf16*)alloc(AB);
  bf16* xk = (bf16*)alloc(AB);
  bf16* xv = (bf16*)alloc(AB);
  char* xwslot = (char*)alloc(AF);    // xwb -> U
  bf16* twb = (bf16*)alloc((size_t)NTOK * 64 * sizeof(bf16));
  float* wlog = (float*)alloc(AF);
  char* scratch24 = (char*)alloc(3 * AF);  // mm_part / qkv_part+y / o_part
  float* dx = (float*)alloc(AF);           // dx -> tw_part (8 MB)
  bf16* yb = (bf16*)alloc(AB);

  bf16* xxxb = (bf16*)xslot;
  bf16* w1t = (bf16*)(xslot + 4 * 1024 * 1024);
  bf16* tdw1t = (bf16*)(xslot + 4 * 1024 * 1024 + 512 * 1024);
  bf16* w2t = (bf16*)(xslot + 4 * 1024 * 1024 + 768 * 1024);
  bf16* tdw2t = (bf16*)(xslot + 4 * 1024 * 1024 + 1280 * 1024);
  bf16* qt = (bf16*)xslot;
  bf16* kt = (bf16*)(xslot + 4 * 1024 * 1024);
  bf16* xwb = (bf16*)xwslot;
  float* U = (float*)xwslot;
  bf16* mmb = (bf16*)mmslot;
  float* aLbuf = (float*)(mmslot + 256 * 1024);

  float* mm_part = (float*)scratch24;   // 16 MB, steps 2-3
  bf16* qkv_part = (bf16*)scratch24;    // 24 MB, steps 5-8 (slices 4,5 live to 8)
  float* y = (float*)scratch24;         // 8 MB, steps 8-9 (overwrites slices 0,1)
  bf16* o_part = (bf16*)scratch24;      // 16 MB, steps 10-11
  float* tw_part = dx;                  // 8 MB, steps 5-6 (dx dead after mproj)

  // 1. fused setup: weight transposes + token shift
  k_setup<<<19200, dim3(32, 8), 0, stream>>>(
      q_w, k_w, v_w, o_w, maa_w1, td_w1, maa_w2, td_w2, x, maa_x, qwt, kwt,
      vwt, owt, w1t, tdw1t, w2t, tdw2t, dx, xxxb);
  // 2-3. mix LoRA stage 1
  k_lora_gemm128<<<dim3(8, NSLICE), 256, 0, stream>>>(xxxb, w1t, mm_part);
  k_reduce_tanh<<<128, 256, 0, stream>>>(mm_part, mmb, NTOK * 128 / 4);
  // 4. mix LoRA stage 2 via MFMA, fused xr/xk/xv/xwb epilogue
  k_mproj_mfma<<<dim3(16, 8, 4), 256, 0, stream>>>(
      mmb, w2t, x, dx, maa_r, maa_k, maa_v, maa_w, xr, xk, xv, xwb);
  // 5. fused: qkv split-K partials + decay-LoRA stage 1 split-K partials
  k_qkv_lora<<<1024, 256, 0, stream>>>(xr, xk, xv, qwt, kwt, vwt, qkv_part,
                                       xwb, tdw1t, tw_part);
  // 5b. reduce decay partials -> twb
  k_reduce_tanh<<<64, 256, 0, stream>>>(tw_part, twb, NTOK * 64 / 4);
  // 6. decay LoRA stage 2 via MFMA -> wlog
  k_tdB_mfma<<<dim3(16, 8), 256, 0, stream>>>(twb, tdw2t, tdcay, wlog);
  // 7. chunked GLA pass 1 (fused qkv combine + k-scale)
  k_chunk_prep<<<512, 256, 0, stream>>>(qkv_part, q_b, k_b, v_b, wlog, qt, kt,
                                        aLbuf, U);
  // 8. chunked GLA pass 2 (carry fused; v combined from partials)
  k_chunk_out<<<512, 256, 0, stream>>>(qt, kt, qkv_part, v_b, U, aLbuf, y);
  // 9. LayerNorm -> bf16
  k_ln<<<NTOK, 256, 0, stream>>>(y, ln_g, ln_b, yb);
  // 10-11. output projection: split-K=4 bf16 partials + combine
  k_gemm_o_split<<<dim3(16, 8, 4), 256, 0, stream>>>(yb, owt, o_part);
  k_combine_o<<<2048, 256, 0, stream>>>(o_part, out);
}